// Round 11
// baseline (150.282 us; speedup 1.0000x reference)
//
#include <hip/hip_runtime.h>

// NonLocalAttention n=4, c=64, hw=6400.
// R23: attn = R15's 64q/wave loop (proven correct, 67.9us at HALF occupancy)
// with KS=10 -> grid (25,4,10)=1000 blocks = ~3.9 blocks/CU (R15 was
// grid-limited at 500). NO setprio: R10's isolated A/B measured it at
// -10us on this lockstep structure (confirms m190; re-attributes R5's
// KS=10 regression to the bundled setprio -> KS=10 alone is ~neutral).
// 64q/wave halves per-q LDS+staging issue load; at full occupancy the
// model says ~52-58us. combine = vectorized (R10-proven, -6.6us), KS=10.
// conv/wprep unchanged (conv 6.7us measured, not a lever).

typedef __attribute__((ext_vector_type(8))) unsigned short us8;
typedef __attribute__((ext_vector_type(4))) unsigned short us4;
typedef __attribute__((ext_vector_type(8))) __bf16 bf16x8;
typedef __attribute__((ext_vector_type(16))) float f32x16;

#define HW 6400
#define L2E 1.44269504088896340736f
#define KS 10
#define ITERS 10  // (HW/KS)/64

union V8 { us8 s; us4 h[2]; bf16x8 b; unsigned u4[4]; };

__device__ __forceinline__ unsigned short f32_to_bf16(float f) {
  unsigned u = __float_as_uint(f);
  u += 0x7fffu + ((u >> 16) & 1u);  // RNE; finite inputs
  return (unsigned short)(u >> 16);
}
__device__ __forceinline__ float bf16_bits_to_f32(unsigned short u) {
  return __uint_as_float(((unsigned)u) << 16);
}
__device__ __forceinline__ unsigned pack_bf16x2(float a, float b) {
#if __has_builtin(__builtin_amdgcn_cvt_pk_bf16_f32)
  auto v = __builtin_amdgcn_cvt_pk_bf16_f32(a, b);
  unsigned u;
  __builtin_memcpy(&u, &v, 4);
  return u;
#else
  unsigned ua = __float_as_uint(a); ua += 0x7fffu + ((ua >> 16) & 1u);
  unsigned ub = __float_as_uint(b); ub += 0x7fffu + ((ub >> 16) & 1u);
  return (ua >> 16) | (ub & 0xffff0000u);
#endif
}

// ---------------------------------------------------------------------------
// wprep: W1..3 (64x64 f32) -> bf16 hi/lo pairs, once. L2E folded into w1/b1.
// ---------------------------------------------------------------------------
__global__ __launch_bounds__(256) void wprep_kernel(
    const float* __restrict__ w1, const float* __restrict__ b1,
    const float* __restrict__ w2, const float* __restrict__ w3,
    unsigned short* __restrict__ Whl, float* __restrict__ b1s) {
  const int tid = blockIdx.x * 256 + threadIdx.x;
  if (tid < 3 * 4096) {
    const int k = tid >> 12;
    const int rem = tid & 4095;
    const float* wsrc = (k == 0) ? w1 : (k == 1) ? w2 : w3;
    float v = wsrc[rem];
    if (k == 0) v *= L2E;
    const unsigned short hi = f32_to_bf16(v);
    const unsigned short lo = f32_to_bf16(v - bf16_bits_to_f32(hi));
    Whl[(size_t)(k * 2) * 4096 + rem] = hi;
    Whl[(size_t)(k * 2 + 1) * 4096 + rem] = lo;
  }
  if (tid < 64) b1s[tid] = b1[tid] * L2E;
}

// ---------------------------------------------------------------------------
// Conv via MFMA: grid (100, 4) x 256 thr. UNCHANGED from R9 (measured
// ~6.7us via R17's z=2 diagnostic; not a lever).
// ---------------------------------------------------------------------------
__global__ __launch_bounds__(256, 2) void conv_kernel(
    const float* __restrict__ x, const unsigned short* __restrict__ Whl,
    const float* __restrict__ b1s, const float* __restrict__ b2,
    const float* __restrict__ b3,
    unsigned short* __restrict__ Qg, unsigned short* __restrict__ Kg,
    unsigned short* __restrict__ Vg) {
  __shared__ __align__(16) unsigned short Xh[64 * 72];  // [pix][ch] bf16 hi
  __shared__ __align__(16) unsigned short Xl[64 * 72];  // [pix][ch] bf16 lo
  __shared__ __align__(16) unsigned short tb[64 * 72];  // [p][c] transpose buf

  const int t = threadIdx.x;
  const int n = blockIdx.y;
  const int p0 = blockIdx.x * 64;
  const int wv = t >> 6;
  const int lane = t & 63;
  const int l31 = lane & 31;
  const int lh = lane >> 5;
  const int ob = (wv & 1) * 32;   // o-row base
  const int pw = (wv >> 1) * 32;  // pixel base within block

  {  // stage + convert X: thread = channel pair 2*c2, 8 pixels pg..pg+7
    const int c2 = t >> 3;
    const int pg = (t & 7) * 8;
    const float* s0 = x + ((size_t)(n * 64 + 2 * c2) * HW + p0 + pg);
    const float* s1 = s0 + HW;
    float a0[8], a1[8];
    *(float4*)(a0) = *(const float4*)s0;
    *(float4*)(a0 + 4) = *(const float4*)(s0 + 4);
    *(float4*)(a1) = *(const float4*)s1;
    *(float4*)(a1 + 4) = *(const float4*)(s1 + 4);
#pragma unroll
    for (int j = 0; j < 8; ++j) {
      const unsigned hp = pack_bf16x2(a0[j], a1[j]);
      const float r0 = a0[j] - bf16_bits_to_f32((unsigned short)(hp & 0xffffu));
      const float r1 = a1[j] - bf16_bits_to_f32((unsigned short)(hp >> 16));
      const unsigned lq = pack_bf16x2(r0, r1);
      ((unsigned*)Xh)[(pg + j) * 36 + c2] = hp;
      ((unsigned*)Xl)[(pg + j) * 36 + c2] = lq;
    }
  }
  __syncthreads();

#pragma unroll 1
  for (int k = 0; k < 3; ++k) {
    const unsigned short* Wh = Whl + (size_t)(k * 2) * 4096;
    const unsigned short* Wl = Wh + 4096;
    const float* bm = (k == 0) ? b1s : (k == 1) ? b2 : b3;

    V8 ah[4], al[4];
#pragma unroll
    for (int kst = 0; kst < 4; ++kst) {
      const int off = (ob + l31) * 64 + kst * 16 + lh * 8;
      ah[kst].s = *(const us8*)(Wh + off);
      al[kst].s = *(const us8*)(Wl + off);
    }

    f32x16 acc;
#pragma unroll
    for (int r = 0; r < 16; ++r) acc[r] = 0.f;

#pragma unroll
    for (int kst = 0; kst < 4; ++kst) {
      V8 bh, bl;
      const int xoff = (pw + l31) * 72 + kst * 16 + lh * 8;
      bh.s = *(const us8*)(Xh + xoff);
      bl.s = *(const us8*)(Xl + xoff);
      acc = __builtin_amdgcn_mfma_f32_32x32x16_bf16(al[kst].b, bh.b, acc, 0, 0, 0);
      acc = __builtin_amdgcn_mfma_f32_32x32x16_bf16(ah[kst].b, bl.b, acc, 0, 0, 0);
      acc = __builtin_amdgcn_mfma_f32_32x32x16_bf16(ah[kst].b, bh.b, acc, 0, 0, 0);
    }

    if (k < 2) {  // Q or K: transpose to [p][c] via LDS, then coalesced store
#pragma unroll
      for (int rq = 0; rq < 4; ++rq) {
        const int o = ob + 8 * rq + 4 * lh;
        const int pcol = pw + l31;
        float v[4];
#pragma unroll
        for (int j = 0; j < 4; ++j) {
          float a = acc[4 * rq + j] + bm[o + j];
          a = fmaxf(a, 0.f) + 0.2f * fminf(a, 0.f);
          v[j] = a;
        }
        unsigned* dst = (unsigned*)(tb + pcol * 72 + o);
        dst[0] = pack_bf16x2(v[0], v[1]);
        dst[1] = pack_bf16x2(v[2], v[3]);
      }
      __syncthreads();
      {
        const int p = t >> 2, part = t & 3;
        const unsigned short* src = tb + p * 72 + part * 16;
        unsigned short* dst = (k == 0 ? Qg : Kg) +
                              (size_t)(n * HW + p0 + p) * 64 + part * 16;
        *(us8*)dst = *(const us8*)src;
        *(us8*)(dst + 8) = *(const us8*)(src + 8);
      }
      __syncthreads();  // tb reused by next conv
    } else {  // V [n,c,p]: direct coalesced 2B stores
#pragma unroll
      for (int r = 0; r < 16; ++r) {
        const int o = ob + 8 * (r >> 2) + 4 * lh + (r & 3);
        const int pcol = pw + l31;
        float a = acc[r] + bm[o];
        a = fmaxf(a, 0.f) + 0.2f * fminf(a, 0.f);
        Vg[(size_t)(n * 64 + o) * HW + p0 + pcol] = f32_to_bf16(a);
      }
    }
  }
}

// ---------------------------------------------------------------------------
// Split-K flash attention, 64q/wave: grid (25, 4, KS=10) x 256 thr (4 waves).
// Wave = 64 q (two 32-q halves sharing K/V fragments); 64 keys/iter.
// BYTE-IDENTICAL loop to R15 (proven correct, 112 VGPR, no spill), no
// setprio. LDS: double-buffered K,V tiles [64][72] bf16 = 36864 B.
// 1000 blocks -> ~3.9 blocks/CU (VGPR 112 and LDS 36.9KB both allow 4).
// ---------------------------------------------------------------------------
__global__ __launch_bounds__(256, 2) void attn_kernel(
    const unsigned short* __restrict__ Qg, const unsigned short* __restrict__ Kg,
    const unsigned short* __restrict__ Vg, unsigned short* __restrict__ Opart,
    float* __restrict__ Lpart) {
  __shared__ __align__(16) char smem[36864];
  // K buffers at 0 / 9216; V buffers at 18432 / 27648 (each [64][72] bf16)
  unsigned short* Otb = (unsigned short*)smem;  // [64][266] bf16 epilogue overlay

  const int t = threadIdx.x;
  const int w = t >> 6;
  const int lane = t & 63;
  const int l31 = lane & 31;
  const int lh = lane >> 5;
  const int nb = blockIdx.y;
  const int qb = blockIdx.x * 256;
  const int ks = blockIdx.z;
  const int key0 = ks * (HW / KS);

  // loop-invariant Q fragments, two q-halves (B operand: col m = l31)
  V8 aQ[2][4];
#pragma unroll
  for (int h = 0; h < 2; ++h) {
    const unsigned short* qrow =
        Qg + (size_t)(nb * HW + qb + w * 64 + h * 32 + l31) * 64 + lh * 8;
#pragma unroll
    for (int kst = 0; kst < 4; ++kst)
      aQ[h][kst].s = *(const us8*)(qrow + kst * 16);
  }

  f32x16 accO[2][2];  // [qhalf][ci]
#pragma unroll
  for (int h = 0; h < 2; ++h)
#pragma unroll
    for (int ci = 0; ci < 2; ++ci)
#pragma unroll
      for (int r = 0; r < 16; ++r) accO[h][ci][r] = 0.f;
  float lp0 = 0.f, lp1 = 0.f;

  // persistent zero seed for the S-phase accumulator
  f32x16 zero16;
#pragma unroll
  for (int r = 0; r < 16; ++r) zero16[r] = 0.f;

  const int soff = (t >> 2) * 72 + (t & 3) * 16;
  const unsigned short* ksrc =
      Kg + (size_t)nb * HW * 64 + (size_t)(key0 + (t >> 2)) * 64 + (t & 3) * 16;
  const unsigned short* vsrc =
      Vg + (size_t)nb * 64 * HW + (size_t)(t >> 2) * HW + key0 + (t & 3) * 16;

  V8 kr0, kr1, vr0, vr1;
  kr0.s = *(const us8*)ksrc;
  kr1.s = *(const us8*)(ksrc + 8);
  vr0.s = *(const us8*)vsrc;
  vr1.s = *(const us8*)(vsrc + 8);
  {  // tile 0 -> buffer 0
    unsigned short* kd = (unsigned short*)smem + soff;
    unsigned short* vd = (unsigned short*)(smem + 18432) + soff;
    *(us8*)kd = kr0.s; *(us8*)(kd + 8) = kr1.s;
    *(us8*)vd = vr0.s; *(us8*)(vd + 8) = vr1.s;
  }
  __syncthreads();

#pragma unroll 1
  for (int jt = 0; jt < ITERS; ++jt) {
    const int b = jt & 1;
    const unsigned short* Kc = (const unsigned short*)(smem + b * 9216);
    const unsigned short* Vc = (const unsigned short*)(smem + 18432 + b * 9216);
    const bool more = (jt + 1 < ITERS);

    if (more) {  // global prefetch of next tile into registers
      kr0.s = *(const us8*)(ksrc + (jt + 1) * 4096);
      kr1.s = *(const us8*)(ksrc + (jt + 1) * 4096 + 8);
      vr0.s = *(const us8*)(vsrc + (jt + 1) * 64);
      vr1.s = *(const us8*)(vsrc + (jt + 1) * 64 + 8);
    }

#pragma unroll
    for (int ni = 0; ni < 2; ++ni) {
      // ---- K fragments for keys ni*32..+31, shared by both q-halves
      V8 ak[4];
#pragma unroll
      for (int kst = 0; kst < 4; ++kst)
        ak[kst].s = *(const us8*)(Kc + (ni * 32 + l31) * 72 + kst * 16 + lh * 8);

      // ---- S-phase + softmax per q-half (S^T = K Q^T, cols m = l31)
      uint2 pkg[2][4];
#pragma unroll
      for (int h = 0; h < 2; ++h) {
        f32x16 sacc = __builtin_amdgcn_mfma_f32_32x32x16_bf16(
            ak[0].b, aQ[h][0].b, zero16, 0, 0, 0);
#pragma unroll
        for (int kst = 1; kst < 4; ++kst)
          sacc = __builtin_amdgcn_mfma_f32_32x32x16_bf16(ak[kst].b,
                                                         aQ[h][kst].b, sacc,
                                                         0, 0, 0);
        float lps = 0.f;
#pragma unroll
        for (int g = 0; g < 4; ++g) {
          const float p0 = __builtin_amdgcn_exp2f(sacc[4 * g + 0]);
          const float p1 = __builtin_amdgcn_exp2f(sacc[4 * g + 1]);
          const float p2 = __builtin_amdgcn_exp2f(sacc[4 * g + 2]);
          const float p3 = __builtin_amdgcn_exp2f(sacc[4 * g + 3]);
          lps += (p0 + p1) + (p2 + p3);
          pkg[h][g].x = pack_bf16x2(p0, p1);
          pkg[h][g].y = pack_bf16x2(p2, p3);
        }
        if (h == 0) lp0 += lps; else lp1 += lps;
      }

      // ---- V fragments (chunk kst = 2ni+kk), shared by both q-halves
      V8 bv[2][2];
#pragma unroll
      for (int ci = 0; ci < 2; ++ci)
#pragma unroll
        for (int kk = 0; kk < 2; ++kk)
          bv[ci][kk].s = *(const us8*)(Vc + (ci * 32 + l31) * 72 +
                                       (2 * ni + kk) * 16 + lh * 8);

      // ---- PV-phase for these 32 keys
#pragma unroll
      for (int kk = 0; kk < 2; ++kk) {
        const int gb = 2 * kk;
#pragma unroll
        for (int h = 0; h < 2; ++h) {
          V8 ap;  // A-frag lo-quad = 4kst+2lh, hi-quad = 4kst+2lh+1
#if __has_builtin(__builtin_amdgcn_permlane32_swap)
          {
            auto rx = __builtin_amdgcn_permlane32_swap(
                pkg[h][gb].x, pkg[h][gb + 1].x, false, false);
            auto ry = __builtin_amdgcn_permlane32_swap(
                pkg[h][gb].y, pkg[h][gb + 1].y, false, false);
            ap.u4[0] = rx[0]; ap.u4[2] = rx[1];
            ap.u4[1] = ry[0]; ap.u4[3] = ry[1];
          }
#else
          {
            const uint2 qa = pkg[h][gb];
            const uint2 qb2 = pkg[h][gb + 1];
            uint2 send;
            send.x = lh ? qa.x : qb2.x;
            send.y = lh ? qa.y : qb2.y;
            uint2 recv;
            recv.x = __shfl_xor(send.x, 32);
            recv.y = __shfl_xor(send.y, 32);
            const uint2 keep = {lh ? qb2.x : qa.x, lh ? qb2.y : qa.y};
            ap.u4[0] = lh ? recv.x : keep.x;
            ap.u4[1] = lh ? recv.y : keep.y;
            ap.u4[2] = lh ? keep.x : recv.x;
            ap.u4[3] = lh ? keep.y : recv.y;
          }
#endif
          accO[h][0] = __builtin_amdgcn_mfma_f32_32x32x16_bf16(
              ap.b, bv[0][kk].b, accO[h][0], 0, 0, 0);
          accO[h][1] = __builtin_amdgcn_mfma_f32_32x32x16_bf16(
              ap.b, bv[1][kk].b, accO[h][1], 0, 0, 0);
        }
      }
    }

    if (more) {  // stage next tile into the other buffer; ONE barrier/iter
      unsigned short* kd = (unsigned short*)(smem + (1 - b) * 9216) + soff;
      unsigned short* vd = (unsigned short*)(smem + 18432 + (1 - b) * 9216) + soff;
      *(us8*)kd = kr0.s; *(us8*)(kd + 8) = kr1.s;
      *(us8*)vd = vr0.s; *(us8*)(vd + 8) = vr1.s;
      __syncthreads();
    }
  }

  // l reduce + store (64 q per wave, two halves)
  {
    const float ls0 = lp0 + __shfl_xor(lp0, 32);
    const float ls1 = lp1 + __shfl_xor(lp1, 32);
    if (lh == 0) {
      float* lrow = Lpart + ((size_t)ks * 4 + nb) * HW + qb + w * 64;
      lrow[l31] = ls0;
      lrow[32 + l31] = ls1;
    }
  }

  // epilogue: Otb[64 c][266] bf16 (odd dword stride -> conflict-free);
  // coalesced us8 stores of [c][256 q].
  __syncthreads();  // all Vc/Kc reads done before smem reuse
#pragma unroll
  for (int h = 0; h < 2; ++h)
#pragma unroll
    for (int ci = 0; ci < 2; ++ci)
#pragma unroll
      for (int r = 0; r < 16; ++r) {
        const int qcol = w * 64 + h * 32 + 8 * (r >> 2) + 4 * lh + (r & 3);
        Otb[(ci * 32 + l31) * 266 + qcol] = f32_to_bf16(accO[h][ci][r]);
      }
  __syncthreads();
  {
    const int ch = t >> 2, part = t & 3;
    const unsigned short* src = Otb + ch * 266 + part * 64;
    unsigned short* dst =
        Opart + (((size_t)ks * 4 + nb) * 64 + ch) * HW + qb + part * 64;
#pragma unroll
    for (int i = 0; i < 8; ++i) {
      V8 v;
      v.h[0] = *(const us4*)(src + i * 8);
      v.h[1] = *(const us4*)(src + i * 8 + 4);
      *(us8*)(dst + i * 8) = v.s;
    }
  }
}

// ---------------------------------------------------------------------------
// Combine: out[n][c][p] = sum_ks O[ks][n][c][p] / sum_ks l[ks][n][p].
// Vectorized: 8 elems/thread (us8 Opart loads), grid 800. Arithmetic order
// identical to the scalar version (ks ascending) -> same absmax.
// ---------------------------------------------------------------------------
__global__ __launch_bounds__(256) void combine_kernel(
    const unsigned short* __restrict__ Opart, const float* __restrict__ Lpart,
    float* __restrict__ out) {
  const int tid = blockIdx.x * 256 + threadIdx.x;
  const size_t e = (size_t)tid * 8;
  float o[8] = {0.f, 0.f, 0.f, 0.f, 0.f, 0.f, 0.f, 0.f};
#pragma unroll
  for (int ks = 0; ks < KS; ++ks) {
    const us8 v = *(const us8*)(Opart + (size_t)ks * (4 * 64 * HW) + e);
#pragma unroll
    for (int j = 0; j < 8; ++j) o[j] += bf16_bits_to_f32(v[j]);
  }
  const int n = (int)(e / (64 * HW));
  const int p = (int)(e % HW);
  float l[8] = {0.f, 0.f, 0.f, 0.f, 0.f, 0.f, 0.f, 0.f};
#pragma unroll
  for (int ks = 0; ks < KS; ++ks) {
    const float* lptr = Lpart + ((size_t)ks * 4 + n) * HW + p;
#pragma unroll
    for (int j = 0; j < 2; ++j) {
      const float4 lv = *(const float4*)(lptr + j * 4);
      l[4 * j + 0] += lv.x; l[4 * j + 1] += lv.y;
      l[4 * j + 2] += lv.z; l[4 * j + 3] += lv.w;
    }
  }
  float* od = out + e;
#pragma unroll
  for (int j = 0; j < 2; ++j) {
    float4 r;
    r.x = o[4 * j + 0] / l[4 * j + 0];
    r.y = o[4 * j + 1] / l[4 * j + 1];
    r.z = o[4 * j + 2] / l[4 * j + 2];
    r.w = o[4 * j + 3] / l[4 * j + 3];
    *(float4*)(od + j * 4) = r;
  }
}

extern "C" void kernel_launch(void* const* d_in, const int* in_sizes, int n_in,
                              void* d_out, int out_size, void* d_ws, size_t ws_size,
                              hipStream_t stream) {
  const float* x = (const float*)d_in[0];
  const float* w1 = (const float*)d_in[1];
  const float* b1 = (const float*)d_in[2];
  const float* w2 = (const float*)d_in[3];
  const float* b2 = (const float*)d_in[4];
  const float* w3 = (const float*)d_in[5];
  const float* b3 = (const float*)d_in[6];
  float* out = (float*)d_out;

  // ws: Q,K,V bf16 (9.8 MB) + Opart bf16 KS=10 (32.8 MB) + Lpart (1.0 MB)
  //     + Whl (48 KB) + b1s (256 B) ~= 43.7 MB
  unsigned short* Q = (unsigned short*)d_ws;
  unsigned short* K = Q + (size_t)4 * HW * 64;
  unsigned short* V = K + (size_t)4 * HW * 64;
  unsigned short* Opart = V + (size_t)4 * HW * 64;
  float* Lpart = (float*)(Opart + (size_t)KS * 4 * 64 * HW);
  unsigned short* Whl = (unsigned short*)(Lpart + (size_t)KS * 4 * HW);
  float* b1s = (float*)(Whl + 3 * 2 * 4096);

  wprep_kernel<<<48, 256, 0, stream>>>(w1, b1, w2, w3, Whl, b1s);
  conv_kernel<<<dim3(100, 4), 256, 0, stream>>>(x, Whl, b1s, b2, b3, Q, K, V);
  attn_kernel<<<dim3(25, 4, KS), 256, 0, stream>>>(Q, K, V, Opart, Lpart);
  combine_kernel<<<800, 256, 0, stream>>>(Opart, Lpart, out);
}

// Round 12
// 142.610 us; speedup vs baseline: 1.0538x; 1.0538x over previous
//
#include <hip/hip_runtime.h>

// NonLocalAttention n=4, c=64, hw=6400.
// R25: CONSOLIDATION — best measured components, no new variables.
// attn = R3's 64.1us loop BYTE-IDENTICAL (32q/wave, KS=5, dist-1 prefetch,
// pitch-72, ONE barrier/iter, permlane32_swap, zero16, NO setprio [R10 A/B:
// -10us on lockstep]). combine = vectorized us8 (R10-proven -6.6us).
// conv/wprep = R9 (conv 6.7us measured via z=2 diag).
// Ledger: fixed ~60 + attn 64.1 + conv 6.7 + combine ~6 + wprep 1.2 ~ 138.
// Dead ends proven: setprio(-10), no-LDS(-100), 64q/wave (AGPR-capped at
// 2 blk/CU: 112 VGPR + 64 AGPR unified = 176/wave), dist-2 prefetch
// (spills at (256,4)), KS=10 (~neutral), conv z-split/VALU-cut (not the
// bottleneck), semaphore-tail combine (agent fences = L2 flush).

typedef __attribute__((ext_vector_type(8))) unsigned short us8;
typedef __attribute__((ext_vector_type(4))) unsigned short us4;
typedef __attribute__((ext_vector_type(8))) __bf16 bf16x8;
typedef __attribute__((ext_vector_type(16))) float f32x16;

#define HW 6400
#define L2E 1.44269504088896340736f
#define KS 5
#define ITERS 20  // (HW/64)/KS

union V8 { us8 s; us4 h[2]; bf16x8 b; unsigned u4[4]; };

__device__ __forceinline__ unsigned short f32_to_bf16(float f) {
  unsigned u = __float_as_uint(f);
  u += 0x7fffu + ((u >> 16) & 1u);  // RNE; finite inputs
  return (unsigned short)(u >> 16);
}
__device__ __forceinline__ float bf16_bits_to_f32(unsigned short u) {
  return __uint_as_float(((unsigned)u) << 16);
}
__device__ __forceinline__ unsigned pack_bf16x2(float a, float b) {
#if __has_builtin(__builtin_amdgcn_cvt_pk_bf16_f32)
  auto v = __builtin_amdgcn_cvt_pk_bf16_f32(a, b);
  unsigned u;
  __builtin_memcpy(&u, &v, 4);
  return u;
#else
  unsigned ua = __float_as_uint(a); ua += 0x7fffu + ((ua >> 16) & 1u);
  unsigned ub = __float_as_uint(b); ub += 0x7fffu + ((ub >> 16) & 1u);
  return (ua >> 16) | (ub & 0xffff0000u);
#endif
}

// ---------------------------------------------------------------------------
// wprep: W1..3 (64x64 f32) -> bf16 hi/lo pairs, once. L2E folded into w1/b1.
// ---------------------------------------------------------------------------
__global__ __launch_bounds__(256) void wprep_kernel(
    const float* __restrict__ w1, const float* __restrict__ b1,
    const float* __restrict__ w2, const float* __restrict__ w3,
    unsigned short* __restrict__ Whl, float* __restrict__ b1s) {
  const int tid = blockIdx.x * 256 + threadIdx.x;
  if (tid < 3 * 4096) {
    const int k = tid >> 12;
    const int rem = tid & 4095;
    const float* wsrc = (k == 0) ? w1 : (k == 1) ? w2 : w3;
    float v = wsrc[rem];
    if (k == 0) v *= L2E;
    const unsigned short hi = f32_to_bf16(v);
    const unsigned short lo = f32_to_bf16(v - bf16_bits_to_f32(hi));
    Whl[(size_t)(k * 2) * 4096 + rem] = hi;
    Whl[(size_t)(k * 2 + 1) * 4096 + rem] = lo;
  }
  if (tid < 64) b1s[tid] = b1[tid] * L2E;
}

// ---------------------------------------------------------------------------
// Conv via MFMA: grid (100, 4) x 256 thr. UNCHANGED from R9 (measured
// ~6.7us via R17's z=2 diagnostic; not a lever).
// ---------------------------------------------------------------------------
__global__ __launch_bounds__(256, 2) void conv_kernel(
    const float* __restrict__ x, const unsigned short* __restrict__ Whl,
    const float* __restrict__ b1s, const float* __restrict__ b2,
    const float* __restrict__ b3,
    unsigned short* __restrict__ Qg, unsigned short* __restrict__ Kg,
    unsigned short* __restrict__ Vg) {
  __shared__ __align__(16) unsigned short Xh[64 * 72];  // [pix][ch] bf16 hi
  __shared__ __align__(16) unsigned short Xl[64 * 72];  // [pix][ch] bf16 lo
  __shared__ __align__(16) unsigned short tb[64 * 72];  // [p][c] transpose buf

  const int t = threadIdx.x;
  const int n = blockIdx.y;
  const int p0 = blockIdx.x * 64;
  const int wv = t >> 6;
  const int lane = t & 63;
  const int l31 = lane & 31;
  const int lh = lane >> 5;
  const int ob = (wv & 1) * 32;   // o-row base
  const int pw = (wv >> 1) * 32;  // pixel base within block

  {  // stage + convert X: thread = channel pair 2*c2, 8 pixels pg..pg+7
    const int c2 = t >> 3;
    const int pg = (t & 7) * 8;
    const float* s0 = x + ((size_t)(n * 64 + 2 * c2) * HW + p0 + pg);
    const float* s1 = s0 + HW;
    float a0[8], a1[8];
    *(float4*)(a0) = *(const float4*)s0;
    *(float4*)(a0 + 4) = *(const float4*)(s0 + 4);
    *(float4*)(a1) = *(const float4*)s1;
    *(float4*)(a1 + 4) = *(const float4*)(s1 + 4);
#pragma unroll
    for (int j = 0; j < 8; ++j) {
      const unsigned hp = pack_bf16x2(a0[j], a1[j]);
      const float r0 = a0[j] - bf16_bits_to_f32((unsigned short)(hp & 0xffffu));
      const float r1 = a1[j] - bf16_bits_to_f32((unsigned short)(hp >> 16));
      const unsigned lq = pack_bf16x2(r0, r1);
      ((unsigned*)Xh)[(pg + j) * 36 + c2] = hp;
      ((unsigned*)Xl)[(pg + j) * 36 + c2] = lq;
    }
  }
  __syncthreads();

#pragma unroll 1
  for (int k = 0; k < 3; ++k) {
    const unsigned short* Wh = Whl + (size_t)(k * 2) * 4096;
    const unsigned short* Wl = Wh + 4096;
    const float* bm = (k == 0) ? b1s : (k == 1) ? b2 : b3;

    V8 ah[4], al[4];
#pragma unroll
    for (int kst = 0; kst < 4; ++kst) {
      const int off = (ob + l31) * 64 + kst * 16 + lh * 8;
      ah[kst].s = *(const us8*)(Wh + off);
      al[kst].s = *(const us8*)(Wl + off);
    }

    f32x16 acc;
#pragma unroll
    for (int r = 0; r < 16; ++r) acc[r] = 0.f;

#pragma unroll
    for (int kst = 0; kst < 4; ++kst) {
      V8 bh, bl;
      const int xoff = (pw + l31) * 72 + kst * 16 + lh * 8;
      bh.s = *(const us8*)(Xh + xoff);
      bl.s = *(const us8*)(Xl + xoff);
      acc = __builtin_amdgcn_mfma_f32_32x32x16_bf16(al[kst].b, bh.b, acc, 0, 0, 0);
      acc = __builtin_amdgcn_mfma_f32_32x32x16_bf16(ah[kst].b, bl.b, acc, 0, 0, 0);
      acc = __builtin_amdgcn_mfma_f32_32x32x16_bf16(ah[kst].b, bh.b, acc, 0, 0, 0);
    }

    if (k < 2) {  // Q or K: transpose to [p][c] via LDS, then coalesced store
#pragma unroll
      for (int rq = 0; rq < 4; ++rq) {
        const int o = ob + 8 * rq + 4 * lh;
        const int pcol = pw + l31;
        float v[4];
#pragma unroll
        for (int j = 0; j < 4; ++j) {
          float a = acc[4 * rq + j] + bm[o + j];
          a = fmaxf(a, 0.f) + 0.2f * fminf(a, 0.f);
          v[j] = a;
        }
        unsigned* dst = (unsigned*)(tb + pcol * 72 + o);
        dst[0] = pack_bf16x2(v[0], v[1]);
        dst[1] = pack_bf16x2(v[2], v[3]);
      }
      __syncthreads();
      {
        const int p = t >> 2, part = t & 3;
        const unsigned short* src = tb + p * 72 + part * 16;
        unsigned short* dst = (k == 0 ? Qg : Kg) +
                              (size_t)(n * HW + p0 + p) * 64 + part * 16;
        *(us8*)dst = *(const us8*)src;
        *(us8*)(dst + 8) = *(const us8*)(src + 8);
      }
      __syncthreads();  // tb reused by next conv
    } else {  // V [n,c,p]: direct coalesced 2B stores
#pragma unroll
      for (int r = 0; r < 16; ++r) {
        const int o = ob + 8 * (r >> 2) + 4 * lh + (r & 3);
        const int pcol = pw + l31;
        float a = acc[r] + bm[o];
        a = fmaxf(a, 0.f) + 0.2f * fminf(a, 0.f);
        Vg[(size_t)(n * 64 + o) * HW + p0 + pcol] = f32_to_bf16(a);
      }
    }
  }
}

// ---------------------------------------------------------------------------
// Split-K flash attention: grid (50, 4, KS) x 256 thr (4 waves), 32 q/wave.
// BYTE-IDENTICAL to the measured 64.1us R3 loop. No setprio.
// LDS: double-buffered K,V tiles [64][72] bf16 = 36864 B; ONE barrier/iter.
// ---------------------------------------------------------------------------
__global__ __launch_bounds__(256, 4) void attn_kernel(
    const unsigned short* __restrict__ Qg, const unsigned short* __restrict__ Kg,
    const unsigned short* __restrict__ Vg, unsigned short* __restrict__ Opart,
    float* __restrict__ Lpart) {
  __shared__ __align__(16) char smem[36864];
  // K buffers at 0 / 9216; V buffers at 18432 / 27648 (each [64][72] bf16)
  unsigned short* Otb = (unsigned short*)smem;  // [64][132] bf16 epilogue overlay

  const int t = threadIdx.x;
  const int w = t >> 6;
  const int lane = t & 63;
  const int l31 = lane & 31;
  const int lh = lane >> 5;
  const int nb = blockIdx.y;
  const int qb = blockIdx.x * 128;
  const int ks = blockIdx.z;
  const int key0 = ks * (HW / KS);

  // loop-invariant Q fragments from global (B operand: col m = l31)
  V8 aQ[4];
  {
    const unsigned short* qrow =
        Qg + (size_t)(nb * HW + qb + w * 32 + l31) * 64 + lh * 8;
#pragma unroll
    for (int kst = 0; kst < 4; ++kst) aQ[kst].s = *(const us8*)(qrow + kst * 16);
  }

  f32x16 accO[2];
#pragma unroll
  for (int ci = 0; ci < 2; ++ci)
#pragma unroll
    for (int r = 0; r < 16; ++r) accO[ci][r] = 0.f;
  float lp = 0.f;

  // persistent zero seed for the S-phase accumulator
  f32x16 zero16;
#pragma unroll
  for (int r = 0; r < 16; ++r) zero16[r] = 0.f;

  const int soff = (t >> 2) * 72 + (t & 3) * 16;
  const unsigned short* ksrc =
      Kg + (size_t)nb * HW * 64 + (size_t)(key0 + (t >> 2)) * 64 + (t & 3) * 16;
  const unsigned short* vsrc =
      Vg + (size_t)nb * 64 * HW + (size_t)(t >> 2) * HW + key0 + (t & 3) * 16;

  V8 kr0, kr1, vr0, vr1;
  kr0.s = *(const us8*)ksrc;
  kr1.s = *(const us8*)(ksrc + 8);
  vr0.s = *(const us8*)vsrc;
  vr1.s = *(const us8*)(vsrc + 8);
  {  // tile 0 -> buffer 0
    unsigned short* kd = (unsigned short*)smem + soff;
    unsigned short* vd = (unsigned short*)(smem + 18432) + soff;
    *(us8*)kd = kr0.s; *(us8*)(kd + 8) = kr1.s;
    *(us8*)vd = vr0.s; *(us8*)(vd + 8) = vr1.s;
  }
  __syncthreads();

#pragma unroll 1
  for (int jt = 0; jt < ITERS; ++jt) {
    const int b = jt & 1;
    const unsigned short* Kc = (const unsigned short*)(smem + b * 9216);
    const unsigned short* Vc = (const unsigned short*)(smem + 18432 + b * 9216);
    const bool more = (jt + 1 < ITERS);

    if (more) {  // global prefetch of next tile into registers
      kr0.s = *(const us8*)(ksrc + (jt + 1) * 4096);
      kr1.s = *(const us8*)(ksrc + (jt + 1) * 4096 + 8);
      vr0.s = *(const us8*)(vsrc + (jt + 1) * 64);
      vr1.s = *(const us8*)(vsrc + (jt + 1) * 64 + 8);
    }

#pragma unroll
    for (int ni = 0; ni < 2; ++ni) {
      // ---- S-phase for keys ni*32..+31 (S^T = K Q^T, cols m = l31)
      V8 ak[4];
#pragma unroll
      for (int kst = 0; kst < 4; ++kst)
        ak[kst].s = *(const us8*)(Kc + (ni * 32 + l31) * 72 + kst * 16 + lh * 8);
      f32x16 sacc =
          __builtin_amdgcn_mfma_f32_32x32x16_bf16(ak[0].b, aQ[0].b, zero16, 0, 0, 0);
#pragma unroll
      for (int kst = 1; kst < 4; ++kst)
        sacc = __builtin_amdgcn_mfma_f32_32x32x16_bf16(ak[kst].b, aQ[kst].b,
                                                       sacc, 0, 0, 0);
      // exp2 + pack; pkg[g] = keys ni*32+8g+4lh+{0..3} for q-col l31
      uint2 pkg[4];
#pragma unroll
      for (int g = 0; g < 4; ++g) {
        const float p0 = __builtin_amdgcn_exp2f(sacc[4 * g + 0]);
        const float p1 = __builtin_amdgcn_exp2f(sacc[4 * g + 1]);
        const float p2 = __builtin_amdgcn_exp2f(sacc[4 * g + 2]);
        const float p3 = __builtin_amdgcn_exp2f(sacc[4 * g + 3]);
        lp += (p0 + p1) + (p2 + p3);
        pkg[g].x = pack_bf16x2(p0, p1);
        pkg[g].y = pack_bf16x2(p2, p3);
      }

      // ---- PV-phase for these 32 keys (chunk kst = 2ni+kk)
      V8 bv[2][2];
#pragma unroll
      for (int ci = 0; ci < 2; ++ci)
#pragma unroll
        for (int kk = 0; kk < 2; ++kk)
          bv[ci][kk].s = *(const us8*)(Vc + (ci * 32 + l31) * 72 +
                                       (2 * ni + kk) * 16 + lh * 8);
#pragma unroll
      for (int kk = 0; kk < 2; ++kk) {
        const int gb = 2 * kk;
        V8 ap;  // A-frag lo-quad = 4kst+2lh, hi-quad = 4kst+2lh+1
#if __has_builtin(__builtin_amdgcn_permlane32_swap)
        {
          auto rx = __builtin_amdgcn_permlane32_swap(pkg[gb].x, pkg[gb + 1].x,
                                                     false, false);
          auto ry = __builtin_amdgcn_permlane32_swap(pkg[gb].y, pkg[gb + 1].y,
                                                     false, false);
          ap.u4[0] = rx[0]; ap.u4[2] = rx[1];
          ap.u4[1] = ry[0]; ap.u4[3] = ry[1];
        }
#else
        {
          const uint2 qa = pkg[gb];
          const uint2 qb2 = pkg[gb + 1];
          uint2 send;
          send.x = lh ? qa.x : qb2.x;
          send.y = lh ? qa.y : qb2.y;
          uint2 recv;
          recv.x = __shfl_xor(send.x, 32);
          recv.y = __shfl_xor(send.y, 32);
          const uint2 keep = {lh ? qb2.x : qa.x, lh ? qb2.y : qa.y};
          ap.u4[0] = lh ? recv.x : keep.x;
          ap.u4[1] = lh ? recv.y : keep.y;
          ap.u4[2] = lh ? keep.x : recv.x;
          ap.u4[3] = lh ? keep.y : recv.y;
        }
#endif
        accO[0] = __builtin_amdgcn_mfma_f32_32x32x16_bf16(ap.b, bv[0][kk].b,
                                                          accO[0], 0, 0, 0);
        accO[1] = __builtin_amdgcn_mfma_f32_32x32x16_bf16(ap.b, bv[1][kk].b,
                                                          accO[1], 0, 0, 0);
      }
    }

    if (more) {  // stage next tile into the other buffer; ONE barrier/iter
      unsigned short* kd = (unsigned short*)(smem + (1 - b) * 9216) + soff;
      unsigned short* vd = (unsigned short*)(smem + 18432 + (1 - b) * 9216) + soff;
      *(us8*)kd = kr0.s; *(us8*)(kd + 8) = kr1.s;
      *(us8*)vd = vr0.s; *(us8*)(vd + 8) = vr1.s;
      __syncthreads();
    }
  }

  // l reduce + store (32 q per wave)
  {
    const float lsum = lp + __shfl_xor(lp, 32);
    if (lh == 0)
      Lpart[((size_t)ks * 4 + nb) * HW + qb + w * 32 + l31] = lsum;
  }

  // epilogue: single pass through Otb[64 c][132] bf16; coalesced us8 stores.
  __syncthreads();  // all Vc/Kc reads done before smem reuse
#pragma unroll
  for (int ci = 0; ci < 2; ++ci)
#pragma unroll
    for (int r = 0; r < 16; ++r) {
      const int qcol = w * 32 + 8 * (r >> 2) + 4 * lh + (r & 3);
      Otb[(ci * 32 + l31) * 132 + qcol] = f32_to_bf16(accO[ci][r]);
    }
  __syncthreads();
  {
    const int ch = t >> 2, part = t & 3;
    const unsigned short* src = Otb + ch * 132 + part * 32;
    unsigned short* dst =
        Opart + (((size_t)ks * 4 + nb) * 64 + ch) * HW + qb + part * 32;
#pragma unroll
    for (int i = 0; i < 4; ++i) {
      V8 v;
      v.h[0] = *(const us4*)(src + i * 8);
      v.h[1] = *(const us4*)(src + i * 8 + 4);
      *(us8*)(dst + i * 8) = v.s;
    }
  }
}

// ---------------------------------------------------------------------------
// Combine: out[n][c][p] = sum_ks O[ks][n][c][p] / sum_ks l[ks][n][p].
// Vectorized: 8 elems/thread (us8 Opart loads), grid 800. Arithmetic order
// identical to the scalar version (ks ascending) -> same absmax.
// ---------------------------------------------------------------------------
__global__ __launch_bounds__(256) void combine_kernel(
    const unsigned short* __restrict__ Opart, const float* __restrict__ Lpart,
    float* __restrict__ out) {
  const int tid = blockIdx.x * 256 + threadIdx.x;
  const size_t e = (size_t)tid * 8;
  float o[8] = {0.f, 0.f, 0.f, 0.f, 0.f, 0.f, 0.f, 0.f};
#pragma unroll
  for (int ks = 0; ks < KS; ++ks) {
    const us8 v = *(const us8*)(Opart + (size_t)ks * (4 * 64 * HW) + e);
#pragma unroll
    for (int j = 0; j < 8; ++j) o[j] += bf16_bits_to_f32(v[j]);
  }
  const int n = (int)(e / (64 * HW));
  const int p = (int)(e % HW);
  float l[8] = {0.f, 0.f, 0.f, 0.f, 0.f, 0.f, 0.f, 0.f};
#pragma unroll
  for (int ks = 0; ks < KS; ++ks) {
    const float* lptr = Lpart + ((size_t)ks * 4 + n) * HW + p;
#pragma unroll
    for (int j = 0; j < 2; ++j) {
      const float4 lv = *(const float4*)(lptr + j * 4);
      l[4 * j + 0] += lv.x; l[4 * j + 1] += lv.y;
      l[4 * j + 2] += lv.z; l[4 * j + 3] += lv.w;
    }
  }
  float* od = out + e;
#pragma unroll
  for (int j = 0; j < 2; ++j) {
    float4 r;
    r.x = o[4 * j + 0] / l[4 * j + 0];
    r.y = o[4 * j + 1] / l[4 * j + 1];
    r.z = o[4 * j + 2] / l[4 * j + 2];
    r.w = o[4 * j + 3] / l[4 * j + 3];
    *(float4*)(od + j * 4) = r;
  }
}

extern "C" void kernel_launch(void* const* d_in, const int* in_sizes, int n_in,
                              void* d_out, int out_size, void* d_ws, size_t ws_size,
                              hipStream_t stream) {
  const float* x = (const float*)d_in[0];
  const float* w1 = (const float*)d_in[1];
  const float* b1 = (const float*)d_in[2];
  const float* w2 = (const float*)d_in[3];
  const float* b2 = (const float*)d_in[4];
  const float* w3 = (const float*)d_in[5];
  const float* b3 = (const float*)d_in[6];
  float* out = (float*)d_out;

  // ws: Q,K,V bf16 (9.8 MB) + Opart bf16 KS=5 (16.4 MB) + Lpart (0.5 MB)
  //     + Whl (48 KB) + b1s (256 B)
  unsigned short* Q = (unsigned short*)d_ws;
  unsigned short* K = Q + (size_t)4 * HW * 64;
  unsigned short* V = K + (size_t)4 * HW * 64;
  unsigned short* Opart = V + (size_t)4 * HW * 64;
  float* Lpart = (float*)(Opart + (size_t)KS * 4 * 64 * HW);
  unsigned short* Whl = (unsigned short*)(Lpart + (size_t)KS * 4 * HW);
  float* b1s = (float*)(Whl + 3 * 2 * 4096);

  wprep_kernel<<<48, 256, 0, stream>>>(w1, b1, w2, w3, Whl, b1s);
  conv_kernel<<<dim3(100, 4), 256, 0, stream>>>(x, Whl, b1s, b2, b3, Q, K, V);
  attn_kernel<<<dim3(50, 4, KS), 256, 0, stream>>>(Q, K, V, Opart, Lpart);
  combine_kernel<<<800, 256, 0, stream>>>(Opart, Lpart, out);
}